// Round 12
// baseline (138.556 us; speedup 1.0000x reference)
//
#include <hip/hip_runtime.h>

#define NB 32
#define NT 15

// Workspace layout (byte offsets):
//  ft1   : 0         (B,30,30,90) u8  (zero-filled in K1)           2592000
//  ft2   : 2592000   (B,13,13,250) u8 (fully written in K2)         1352000
//  PosS2 : 11513728  (25,256) f32                                     25600
//  PosS3 : 11539328  (25,200) f32                                     20000
//  W2e   : 11559328  (169,256) f32                                   173056
//  W3s   : 11732384  (16,200) f32                                     12800
//  nzc1  : 11786912  (B,30,30) u8  (zeroed in K1)                     28800
//  nzc2  : 11815712  (B,169) u8   (fully written in K2)                5408
//  nzb1  : 11821120  (32) u8 per-image any-nonzero-ft1                  32
//  nzb2  : 11821152  (32) u8 per-image any-nonzero-ft2 (hard)           32
//  nzg2  : 11821184  (4) i32: [0]=any f,p with W2e<=10, [1]=max(w2) bits 16
//  lcnt  : 11821200  (32) i32 per-image hard count (ends 11821328)      128
//  list1 : 11821440  (B segments of 900) i32                         115200
//  (in-kernel zero region: nzc1..nzg2 = 34288 B = 2143 uint4; lcnt excluded)
//  NOTE: conv2 walks carry an ALGEBRAIC SKIP: if W - max(w2)*nnz > 10 for all
//  lanes, the full walk provably returns ftv=0 (the fill value) — elided.

__device__ __forceinline__ float gather8(const int* lst, int i, const char* wb) {
    int4 p0 = *(const int4*)(lst + i);
    int4 p1 = *(const int4*)(lst + i + 4);
    int o0 = __builtin_amdgcn_readfirstlane(p0.x);
    int o1 = __builtin_amdgcn_readfirstlane(p0.y);
    int o2 = __builtin_amdgcn_readfirstlane(p0.z);
    int o3 = __builtin_amdgcn_readfirstlane(p0.w);
    int o4 = __builtin_amdgcn_readfirstlane(p1.x);
    int o5 = __builtin_amdgcn_readfirstlane(p1.y);
    int o6 = __builtin_amdgcn_readfirstlane(p1.z);
    int o7 = __builtin_amdgcn_readfirstlane(p1.w);
    float a0 = *(const float*)(wb + o0);
    float a1 = *(const float*)(wb + o1);
    float a2 = *(const float*)(wb + o2);
    float a3 = *(const float*)(wb + o3);
    float a4 = *(const float*)(wb + o4);
    float a5 = *(const float*)(wb + o5);
    float a6 = *(const float*)(wb + o6);
    float a7 = *(const float*)(wb + o7);
    return ((a0 + a1) + (a2 + a3)) + ((a4 + a5) + (a6 + a7));
}

// Tail gather: n in [1,8) real entries (uniform), rest literal 0.0f — same tree
// shape as gather8 with trailing zero pads => bit-identical contribution.
__device__ __forceinline__ float gatherN(const int* lst, int i, int n, const char* wb) {
    float a[8];
#pragma unroll
    for (int k = 0; k < 8; k++) {
        float v = 0.f;
        if (k < n) {
            int o = __builtin_amdgcn_readfirstlane(lst[i + k]);
            v = *(const float*)(wb + o);
        }
        a[k] = v;
    }
    return ((a[0] + a[1]) + (a[2] + a[3])) + ((a[4] + a[5]) + (a[6] + a[7]));
}

// ---------- K1: PosS2/PosS3 + zero-fills + per-image conv1 screen ----------
__global__ __launch_bounds__(256) void k_pre(const float* __restrict__ inp,
                                             const float* __restrict__ w1,
                                             const float* __restrict__ w2,
                                             const float* __restrict__ w3,
                                             float* __restrict__ PosS2, float* __restrict__ PosS3,
                                             unsigned char* __restrict__ ft1,
                                             unsigned char* __restrict__ nzc1,
                                             int* __restrict__ lcnt, int* __restrict__ list1) {
    int blk = blockIdx.x, tid = threadIdx.x;
    if (blk < 25) {
        int idx = blk * 256 + tid;
        if (idx < 6250) {
            int f = idx / 25, pos = idx - f * 25;
            float acc = 0.f;
#pragma unroll 9
            for (int c = 0; c < 90; c++) acc += w2[(size_t)(f * 90 + c) * 25 + pos];
            PosS2[pos * 256 + f] = acc;
        }
    } else if (blk < 45) {
        int idx = (blk - 25) * 256 + tid;
        if (idx < 5000) {
            int f = idx / 25, pos = idx - f * 25;
            float acc = 0.f;
#pragma unroll 10
            for (int c = 0; c < 250; c++) acc += w3[(size_t)(f * 250 + c) * 25 + pos];
            PosS3[pos * 200 + f] = acc;
        }
    } else if (blk < 678) {
        int i = (blk - 45) * 256 + tid;
        if (i < 162000) ((uint4*)ft1)[i] = uint4{0, 0, 0, 0};
    } else if (blk < 687) {
        // zero nzc1+nzc2+nzb1+nzb2+nzg2[0..3] (contiguous 34288 B = 2143 uint4)
        int i = (blk - 678) * 256 + tid;
        if (i < 2143) ((uint4*)nzc1)[i] = uint4{0, 0, 0, 0};
    } else {
        // per-image conv1 screen (32 blocks)
        int b = blk - 687;
        __shared__ unsigned char zl[36][36];
        __shared__ unsigned short rs[36][30];
        __shared__ float wm4[4];
        __shared__ float m1s;
        __shared__ int lc;
        for (int i = tid; i < 1296; i += 256) ((unsigned char*)zl)[i] = 0;
        if (tid == 0) lc = 0;
        __syncthreads();
#pragma unroll
        for (int k = 0; k < 4; k++) {
            int pix = tid + k * 256;
            int y = pix >> 5, x = pix & 31;
            const float* p = inp + (size_t)b * 276480 + y * 32 + x;   // t=0, c=0
            int z = 0;
#pragma unroll
            for (int c = 0; c < 18; c++) z += (p[(size_t)c * 1024] != 0.f);
            zl[y + 2][x + 2] = (unsigned char)z;
        }
        float m = 1e30f;
        const float4* w4 = (const float4*)w1;
        for (int i = tid; i < 19845; i += 256) {
            float4 v = w4[i];
            m = fminf(m, fminf(fminf(v.x, v.y), fminf(v.z, v.w)));
        }
        for (int o = 32; o > 0; o >>= 1) m = fminf(m, __shfl_down(m, o));
        if ((tid & 63) == 0) wm4[tid >> 6] = m;
        __syncthreads();
        if (tid == 0) m1s = fminf(fminf(wm4[0], wm4[1]), fminf(wm4[2], wm4[3]));
        __syncthreads();
        for (int i = tid; i < 1080; i += 256) {
            int y = i / 30, x = i - (i / 30) * 30;
            int s = 0;
#pragma unroll
            for (int d = 0; d < 7; d++) s += zl[y][x + d];
            rs[y][x] = (unsigned short)s;
        }
        __syncthreads();
        float m1 = m1s;
        for (int i = tid; i < 900; i += 256) {
            int oy = i / 30, ox = i - (i / 30) * 30;
            int s = 0;
#pragma unroll
            for (int d = 0; d < 7; d++) s += rs[oy + d][ox];
            if (!((float)s * m1 > 15.0f)) {
                int pos = atomicAdd(&lc, 1);
                list1[b * 900 + pos] = b * 900 + i;
            }
        }
        __syncthreads();
        if (tid == 0) lcnt[b] = lc;
    }
}

// ---------- K2: conv1 hard walks (512) + W2e/ft2-fill/nzc2/nzg2 (169) + W3s (16) + w2max (8) ----------
__global__ __launch_bounds__(256) void k_conv1(const float* __restrict__ inp,
                                               const float* __restrict__ w1,
                                               const float* __restrict__ w2,
                                               const float* __restrict__ PosS2,
                                               const float* __restrict__ PosS3,
                                               const int* __restrict__ lcnt,
                                               const int* __restrict__ list1,
                                               unsigned char* __restrict__ ft1,
                                               unsigned char* __restrict__ nzc1,
                                               unsigned char* __restrict__ nzb1,
                                               float* __restrict__ W2e,
                                               unsigned char* __restrict__ ft2,
                                               unsigned char* __restrict__ nzc2,
                                               int* __restrict__ nzg2,
                                               float* __restrict__ W3s) {
    __shared__ __align__(16) int slist[896];
    __shared__ int scnt;
    __shared__ int sbase[33];
    int blk = blockIdx.x, tid = threadIdx.x;
    if (blk < 512) {
        if (tid == 0) {
            int n = 0;
#pragma unroll
            for (int b = 0; b < NB; b++) { sbase[b] = n; n += lcnt[b]; }
            sbase[NB] = n;
        }
        __syncthreads();
        int n1 = sbase[NB];
        for (int it = blk; it < n1; it += 512) {
            __syncthreads();
            int sb = 0;
            while (sb < NB - 1 && it >= sbase[sb + 1]) sb++;
            int idx = list1[sb * 900 + (it - sbase[sb])];
            int b = idx / 900, p = idx - b * 900;
            int oy = p / 30, ox = p - oy * 30;
            unsigned char myft[4];
#pragma unroll
            for (int k = 0; k < 4; k++) {
                int j = tid + k * 256;
                unsigned char v = 255;
                if (j < 882) {
                    int dy = j / 126, rem = j - dy * 126;
                    int dx = rem / 18, c = rem - dx * 18;
                    int y = oy + dy - 2, x = ox + dx - 2;
                    v = 15;
                    if ((unsigned)y < 32u && (unsigned)x < 32u)
                        v = (inp[(size_t)b * 276480 + (size_t)c * 1024 + y * 32 + x] != 0.f) ? 0 : 200;
                }
                myft[k] = v;
            }
            int f = tid < 90 ? tid : 89;
            const char* wb = (const char*)(w1 + (size_t)f * 882);   // [f][c][ky][kx]
            float acc = 0.f; int ftv = 15;
            for (int s = 0; s < 15; s++) {
                if (s == 1) {
#pragma unroll
                    for (int k = 0; k < 4; k++) {
                        if (myft[k] == 200) {
                            int j = tid + k * 256;
                            int dy = j / 126, rem = j - dy * 126;
                            int dx = rem / 18, c = rem - dx * 18;
                            int y = oy + dy - 2, x = ox + dx - 2;
                            const float* q = inp + (size_t)b * 276480 + (size_t)c * 1024 + y * 32 + x;
                            int cf = 0;
#pragma unroll
                            for (int t = 1; t < NT; t++) cf += (q[(size_t)t * 18432] != 0.f);
                            myft[k] = (unsigned char)(15 - cf);
                        }
                    }
                }
                if (tid == 0) scnt = 0;
                __syncthreads();
#pragma unroll
                for (int k = 0; k < 4; k++) {
                    if ((int)myft[k] == s) {
                        int j = tid + k * 256;
                        int dy = j / 126, rem = j - dy * 126;
                        int dx = rem / 18, c = rem - dx * 18;
                        int pp = atomicAdd(&scnt, 1);
                        slist[pp] = (c * 49 + dy * 7 + dx) * 4;     // byte offset in w1[f]
                    }
                }
                __syncthreads();
                int c0 = scnt;
                int full = c0 & ~7;
                for (int i = 0; i < full; i += 8) acc += gather8(slist, i, wb);
                int nt = c0 - full;
                if (nt) acc += gatherN(slist, full, nt, wb);
                if (ftv == 15 && acc > 15.0f) ftv = s;
                if (__syncthreads_and(ftv != 15)) break;
            }
            if (tid < 90) {
                ft1[(size_t)idx * 90 + tid] = (unsigned char)ftv;
                if (ftv != 0) { nzc1[idx] = 1; nzb1[b] = 1; }
            }
            __syncthreads();
        }
    } else if (blk < 681) {
        // per-p: W2e (same pos-ascending order) + ft2 fill + nzc2 init + nzg2
        int p = blk - 512;
        int oy = p / 13, ox = p - oy * 13;
        int f = tid < 250 ? tid : 249;
        float W = 0.f;
#pragma unroll
        for (int pos = 0; pos < 25; pos++) {
            int r = pos / 5, x = pos - r * 5;
            int gy = oy + r, gx = ox + x;
            if (!(gy == 0 || gy == 16 || gx == 0 || gx == 16)) W += PosS2[pos * 256 + f];
        }
        if (tid < 250) W2e[p * 256 + tid] = W;
        unsigned char v = (W > 10.0f) ? 0 : 15;
        if (tid < 250)
            for (int b = 0; b < NB; b++) ft2[(size_t)(b * 169 + p) * 250 + tid] = v;
        int nz = (tid < 250 && W <= 10.0f) ? 1 : 0;
        int any = __syncthreads_or(nz);
        if (tid < NB) nzc2[tid * 169 + p] = (unsigned char)any;
        if (tid == 0 && any) nzg2[0] = 1;
    } else if (blk < 697) {
        // per-px: W3s (same (r,x)-ascending order)
        int px = blk - 681;
        int f = tid < 200 ? tid : 199;
        int oy = px >> 2, ox = px & 3;
        int r0 = max(0, 2 - oy), r1 = min(4, 5 - oy);
        int x0 = max(0, 2 - ox), x1 = min(4, 5 - ox);
        float s = 0.f;
        for (int r = r0; r <= r1; r++)
            for (int x = x0; x <= x1; x++) s += PosS3[(r * 5 + x) * 200 + f];
        if (tid < 200) W3s[px * 200 + tid] = s;
    } else {
        // w2 global max (8 blocks) -> nzg2[1] via int atomicMax (w2 > 0)
        __shared__ float wmx[4];
        float m = -1e30f;
        const float4* w4 = (const float4*)w2;
        for (int i = (blk - 697) * 256 + tid; i < 140625; i += 2048) {
            float4 v = w4[i];
            m = fmaxf(m, fmaxf(fmaxf(v.x, v.y), fmaxf(v.z, v.w)));
        }
        for (int o = 32; o > 0; o >>= 1) m = fmaxf(m, __shfl_down(m, o));
        if ((tid & 63) == 0) wmx[tid >> 6] = m;
        __syncthreads();
        if (tid == 0) {
            float mm = fmaxf(fmaxf(wmx[0], wmx[1]), fmaxf(wmx[2], wmx[3]));
            atomicMax(nzg2 + 1, __float_as_int(mm));
        }
    }
}

// ---------- K3: conv2 screen + algebraic-skip walks + out pot fill ----------
__global__ __launch_bounds__(256) void k_conv2(const unsigned char* __restrict__ ft1,
                                               const unsigned char* __restrict__ nzc1,
                                               const unsigned char* __restrict__ nzb1,
                                               const float* __restrict__ w2,
                                               const float* __restrict__ W2e,
                                               const float* __restrict__ W3s,
                                               const int* __restrict__ m2,
                                               unsigned char* __restrict__ ft2,
                                               unsigned char* __restrict__ nzc2,
                                               unsigned char* __restrict__ nzb2,
                                               float* __restrict__ out) {
    constexpr int PADCAP = 2250 + 15 * 8;
    __shared__ __align__(16) int perm[PADCAP];
    __shared__ int start[16], cur[16], rcnt[15];
    __shared__ int cntCs, anynz;
    int blk = blockIdx.x, tid = threadIdx.x;
    if (blk >= 5408) {
        int i = (blk - 5408) * 256 + tid;          // < 384000 exactly (1500 blocks)
        int g = i * 4;
        int px0 = g & 15;
        int f = (g >> 4) % 200;
        float4 v;
        v.x = W3s[(px0 + 0) * 200 + f];
        v.y = W3s[(px0 + 1) * 200 + f];
        v.z = W3s[(px0 + 2) * 200 + f];
        v.w = W3s[(px0 + 3) * 200 + f];
        *(float4*)(out + 32 + (size_t)g) = v;
        return;
    }
    int idx = blk;
    int b = idx / 169, p = idx - b * 169;
    if (nzb1[b] == 0) return;
    int oy = p / 13, ox = p - oy * 13;
    int gy0 = max(1, oy), gy1 = min(15, oy + 4);
    int gx0 = max(1, ox), gx1 = min(15, ox + 4);
    int y0 = 2 * (gy0 - 1), y1 = 2 * (gy1 - 1) + 1;
    int x0 = 2 * (gx0 - 1), x1 = 2 * (gx1 - 1) + 1;
    int Wd = x1 - x0 + 1, cells = (y1 - y0 + 1) * Wd;
    const unsigned char* nb = nzc1 + b * 900;
    int v = 0;
    if (tid < cells) { int yy = y0 + tid / Wd, xx = x0 + tid % Wd; v = nb[yy * 30 + xx]; }
    int dirty = __syncthreads_or(v);
    if (!dirty) return;
    const unsigned char* fb = ft1 + (size_t)b * 81000;
    if (tid == 0) { cntCs = 0; anynz = 0; }
    if (tid < 16) cur[tid] = 0;
    unsigned char myft[9];
    int nc = 0;
#pragma unroll
    for (int k = 0; k < 9; k++) {
        int j = tid + k * 256;
        myft[k] = 0;
        if (j < 2250) {
            int r = j / 450, rem = j - r * 450;
            int x = rem / 90, c = rem - x * 90;
            int gy = oy + r, gx = ox + x;
            if (gy >= 1 && gy <= 15 && gx >= 1 && gx <= 15) {
                const unsigned char* q = fb + ((size_t)((gy - 1) * 2) * 30 + (gx - 1) * 2) * 90 + c;
                int m = q[0];
                m = min(m, (int)q[90]);
                m = min(m, (int)q[2700]);
                m = min(m, (int)q[2790]);
                myft[k] = (unsigned char)m;
            }
        }
        nc += (myft[k] >= 1);
    }
    for (int o = 32; o > 0; o >>= 1) nc += __shfl_down(nc, o);
    __syncthreads();
    if ((tid & 63) == 0) atomicAdd(&cntCs, nc);
    __syncthreads();
    int f = tid < 250 ? tid : 249;
    float W = W2e[p * 256 + f];
    int ftv;
    if (cntCs == 0) {
        ftv = (W > 10.0f) ? 0 : 15;
    } else {
        // ALGEBRAIC SKIP: R_total <= max(w2)*nnz; if W - that > 10 for every lane,
        // the full walk provably yields ftv=0 for every f (pot at j=0 already > 10).
        float m2f = __int_as_float(m2[1]);
        int skip = __syncthreads_and(W - m2f * (float)cntCs > 10.0f);
        if (skip) {
            if (tid < 250) ft2[(size_t)idx * 250 + tid] = 0;
            __syncthreads();
            if (tid == 0) nzc2[idx] = 0;
            return;
        }
#pragma unroll
        for (int k = 0; k < 9; k++) { int vv = myft[k]; if (vv >= 1) atomicAdd(&cur[vv - 1], 1); }
        __syncthreads();
        if (tid < 15) rcnt[tid] = cur[tid];
        if (tid == 0) {
            int s = 0;
#pragma unroll
            for (int j = 0; j < 15; j++) { int c = cur[j]; start[j] = s; s += (c + 7) & ~7; }
            start[15] = s;
        }
        __syncthreads();
        if (tid < 15) cur[tid] = start[tid];
        __syncthreads();
#pragma unroll
        for (int k = 0; k < 9; k++) {
            int vv = myft[k];
            if (vv >= 1) {
                int j = tid + k * 256;
                int r = j / 450, rem = j - r * 450;
                int x = rem / 90, c = rem - x * 90;
                int pp = atomicAdd(&cur[vv - 1], 1);
                perm[pp] = (c * 25 + (r * 5 + x)) * 4;   // byte offset in w2[f]
            }
        }
        __syncthreads();
        const char* wb = (const char*)(w2 + (size_t)f * 2250);   // [f][c][pos]
        float R = 0.f; int ft = 15;
        for (int j = 14; j >= 0; j--) {
            int sjb = start[j];
            int rc = rcnt[j];
            int rend = sjb + rc;
            int i = sjb;
            for (; i + 8 <= rend; i += 8) R += gather8(perm, i, wb);
            int nt = rend - i;
            if (nt > 0) R += gatherN(perm, i, nt, wb);
            float pot = W - R;
            if (pot > 10.0f) ft = j;
            if (sjb == 0) { if (pot > 10.0f) ft = 0; break; }
            if (__all(pot <= 10.0f)) break;
        }
        ftv = ft;
    }
    if (tid < 250) {
        ft2[(size_t)idx * 250 + tid] = (unsigned char)ftv;
        if (ftv != 0) anynz = 1;
    }
    __syncthreads();
    if (tid == 0) {
        nzc2[idx] = (unsigned char)(anynz ? 1 : 0);
        if (anynz) nzb2[b] = 1;
    }
}

// ---------- K4: per-image conv3 (prefiltered screens + rare walks, direct-w3) + winner ----------
__global__ __launch_bounds__(256) void k_conv3w(const unsigned char* __restrict__ ft2,
                                                const unsigned char* __restrict__ nzc2,
                                                const unsigned char* __restrict__ nzb2,
                                                const int* __restrict__ nzg2,
                                                const float* __restrict__ w3,
                                                const float* __restrict__ W3s,
                                                float* __restrict__ out) {
    constexpr int PADCAP = 4000 + 15 * 8;
    __shared__ __align__(16) int perm[PADCAP];
    __shared__ int start[16], cur[16], rcnt[15];
    __shared__ int fbs[16], rowb[16];
    __shared__ float sv[256];
    __shared__ int   si[256];
    int b = blockIdx.x, tid = threadIdx.x;
    int maybe = nzg2[0] | (int)nzb2[b];
    if (maybe) {
        for (int p = 0; p < 16; p++) {
            int oy = p >> 2, ox = p & 3;
            int r0 = max(0, 2 - oy), r1 = min(4, 5 - oy);
            int x0 = max(0, 2 - ox), x1 = min(4, 5 - ox);
            int py0 = oy + r0 - 2, py1 = oy + r1 - 2;
            int qx0 = ox + x0 - 2, qx1 = ox + x1 - 2;
            int sy0 = 3 * py0, sy1 = 3 * py1 + 2;
            int sx0 = 3 * qx0, sx1 = 3 * qx1 + 2;
            int Wd = sx1 - sx0 + 1, cells = (sy1 - sy0 + 1) * Wd;
            const unsigned char* nb2 = nzc2 + b * 169;
            int v = 0;
            if (tid < cells) { int yy = sy0 + tid / Wd, xx = sx0 + tid % Wd; v = nb2[yy * 13 + xx]; }
            int dirty = __syncthreads_or(v);
            if (!dirty) continue;
            int VR = r1 - r0 + 1, VC = x1 - x0 + 1;
            int NP = VR * VC, NV = NP * 250;
            const unsigned char* fb = ft2 + (size_t)b * 42250;
            if (tid < NP) {
                int rv = tid / VC, xv = tid - rv * VC;
                int py = oy + r0 + rv - 2, pxx = ox + x0 + xv - 2;
                fbs[tid]  = (py * 3 * 13 + pxx * 3) * 250;
                rowb[tid] = (r0 + rv) * 5 + (x0 + xv);          // position index 0..24
            }
            if (tid < 16) cur[tid] = 0;
            __syncthreads();
            unsigned char myft[16];
#pragma unroll
            for (int k = 0; k < 16; k++) {
                int i = tid + k * 256;
                myft[k] = 0;
                if (i < NV) {
                    int posv = i / 250, c = i - posv * 250;
                    const unsigned char* q = fb + fbs[posv] + c;
                    int m = q[0];
#pragma unroll
                    for (int dy = 0; dy < 3; dy++)
#pragma unroll
                        for (int dx = 0; dx < 3; dx++)
                            if (dy | dx) m = min(m, (int)q[(dy * 13 + dx) * 250]);
                    myft[k] = (unsigned char)m;
                }
            }
#pragma unroll
            for (int k = 0; k < 16; k++) { int vv = myft[k]; if (vv >= 1) atomicAdd(&cur[vv - 1], 1); }
            __syncthreads();
            if (tid < 15) rcnt[tid] = cur[tid];
            if (tid == 0) {
                int s = 0;
#pragma unroll
                for (int j = 0; j < 15; j++) { int c = cur[j]; start[j] = s; s += (c + 7) & ~7; }
                start[15] = s;
            }
            __syncthreads();
            if (tid < 15) cur[tid] = start[tid];
            __syncthreads();
#pragma unroll
            for (int k = 0; k < 16; k++) {
                int vv = myft[k];
                if (vv >= 1) {
                    int i = tid + k * 256;
                    int posv = i / 250, c = i - posv * 250;
                    int pp = atomicAdd(&cur[vv - 1], 1);
                    perm[pp] = (c * 25 + rowb[posv]) * 4;       // byte offset in w3[f]
                }
            }
            __syncthreads();

            int f = tid < 200 ? tid : 199;
            const char* wb = (const char*)(w3 + (size_t)f * 6250);   // [f][c][pos]
            float W = W3s[p * 200 + f];
            float* o = out + 32 + ((size_t)b * NT) * 3200 + f * 16 + p;
            float R = 0.f;
            for (int j = 14; j >= 0; j--) {
                int sjb = start[j];
                int rc = rcnt[j];
                int rend = sjb + rc;
                int i = sjb;
                for (; i + 8 <= rend; i += 8) R += gather8(perm, i, wb);
                int nt = rend - i;
                if (nt > 0) R += gatherN(perm, i, nt, wb);
                float pot = W - R;
                if (tid < 200) o[(size_t)j * 3200] = pot;
                if (sjb == 0) {
                    for (int jj = j - 1; jj >= 0; jj--)
                        if (tid < 200) o[(size_t)jj * 3200] = pot;
                    break;
                }
            }
            __syncthreads();
        }
    }
    __syncthreads();
    // winner (verified body)
    const float* p14 = out + 32 + ((size_t)b * NT + 14) * 3200;
    float m = 0.f;
    for (int j = tid; j < 3200; j += 256) {
        float v = p14[j];
        if (v > 0.f && v > m) m = v;
    }
    sv[tid] = m;
    __syncthreads();
    for (int s = 128; s > 0; s >>= 1) {
        if (tid < s) sv[tid] = fmaxf(sv[tid], sv[tid + s]);
        __syncthreads();
    }
    float vofs = 15.f * sv[0];
    __syncthreads();
    float bestv = 0.f; int besti = 0x3fffffff;
    for (int j = tid; j < 3200; j += 256) {
        float v = p14[j];
        float tot = (v > 0.f) ? v + vofs : 0.f;
        if (tot > bestv) { bestv = tot; besti = j; }
    }
    sv[tid] = bestv; si[tid] = besti;
    __syncthreads();
    for (int s = 128; s > 0; s >>= 1) {
        if (tid < s) {
            if (sv[tid + s] > sv[tid] || (sv[tid + s] == sv[tid] && si[tid + s] < si[tid])) {
                sv[tid] = sv[tid + s]; si[tid] = si[tid + s];
            }
        }
        __syncthreads();
    }
    if (tid == 0) {
        float mx = sv[0];
        int cls = (mx != 0.f) ? ((si[0] / 16) / 20) : -1;
        out[b] = (float)cls;
    }
}

extern "C" void kernel_launch(void* const* d_in, const int* in_sizes, int n_in,
                              void* d_out, int out_size, void* d_ws, size_t ws_size,
                              hipStream_t stream) {
    const float* inp = (const float*)d_in[0];
    const float* w1  = (const float*)d_in[1];
    const float* w2  = (const float*)d_in[2];
    const float* w3  = (const float*)d_in[3];
    float* out = (float*)d_out;

    unsigned char* ws   = (unsigned char*)d_ws;
    unsigned char* ft1  = ws + 0;
    unsigned char* ft2  = ws + 2592000;
    float* PosS2 = (float*)(ws + 11513728);
    float* PosS3 = (float*)(ws + 11539328);
    float* W2e   = (float*)(ws + 11559328);
    float* W3s   = (float*)(ws + 11732384);
    unsigned char* nzc1 = ws + 11786912;
    unsigned char* nzc2 = ws + 11815712;
    unsigned char* nzb1 = ws + 11821120;
    unsigned char* nzb2 = ws + 11821152;
    int* nzg2  = (int*)(ws + 11821184);
    int* lcnt  = (int*)(ws + 11821200);
    int* list1 = (int*)(ws + 11821440);

    hipLaunchKernelGGL(k_pre, dim3(719), dim3(256), 0, stream,
                       inp, w1, w2, w3, PosS2, PosS3, ft1, nzc1, lcnt, list1);
    hipLaunchKernelGGL(k_conv1, dim3(705), dim3(256), 0, stream,
                       inp, w1, w2, PosS2, PosS3, lcnt, list1, ft1, nzc1, nzb1, W2e, ft2, nzc2, nzg2, W3s);
    hipLaunchKernelGGL(k_conv2, dim3(6908), dim3(256), 0, stream,
                       ft1, nzc1, nzb1, w2, W2e, W3s, nzg2, ft2, nzc2, nzb2, out);
    hipLaunchKernelGGL(k_conv3w, dim3(NB), dim3(256), 0, stream,
                       ft2, nzc2, nzb2, nzg2, w3, W3s, out);
}

// Round 13
// 134.543 us; speedup vs baseline: 1.0298x; 1.0298x over previous
//
#include <hip/hip_runtime.h>

#define NB 32
#define NT 15

// Workspace layout (byte offsets):
//  ft1   : 0         (B,30,30,90) u8  (zero-filled in K1)           2592000
//  ft2   : 2592000   (B,13,13,250) u8 (fully written in K2)         1352000
//  PosS2 : 11513728  (25,256) f32                                     25600
//  PosS3 : 11539328  (25,200) f32                                     20000
//  W2e   : 11559328  (169,256) f32                                   173056
//  W3s   : 11732384  (16,200) f32                                     12800
//  nzc1  : 11786912  (B,30,30) u8  (zeroed in K1)                     28800
//  nzc2  : 11815712  (B,169) u8   (fully written in K2)                5408
//  nzb1  : 11821120  (32) u8 per-image any-nonzero-ft1                  32
//  nzb2  : 11821152  (32) u8 per-image any-nonzero-ft2 (hard)           32
//  nzg2  : 11821184  (4) i32: [0]=any f,p with W2e<=10, [1]=max(w2) bits 16
//  lcnt  : 11821200  (32) i32 per-image hard count (ends 11821328)      128
//  list1 : 11821440  (B segments of 900) i32                         115200
//  NOTE: conv2 dirty blocks carry a TWO-TIER ALGEBRAIC SKIP, both write-free:
//  tier1 (before pooling): nnz <= 90*dirtyPooledCells; tier2 (exact cntCs).
//  Either skip implies W>10 for all f, so K2's prefill (ft2=0,nzc2=0) is
//  already the exact walk output.

__device__ __forceinline__ float gather8(const int* lst, int i, const char* wb) {
    int4 p0 = *(const int4*)(lst + i);
    int4 p1 = *(const int4*)(lst + i + 4);
    int o0 = __builtin_amdgcn_readfirstlane(p0.x);
    int o1 = __builtin_amdgcn_readfirstlane(p0.y);
    int o2 = __builtin_amdgcn_readfirstlane(p0.z);
    int o3 = __builtin_amdgcn_readfirstlane(p0.w);
    int o4 = __builtin_amdgcn_readfirstlane(p1.x);
    int o5 = __builtin_amdgcn_readfirstlane(p1.y);
    int o6 = __builtin_amdgcn_readfirstlane(p1.z);
    int o7 = __builtin_amdgcn_readfirstlane(p1.w);
    float a0 = *(const float*)(wb + o0);
    float a1 = *(const float*)(wb + o1);
    float a2 = *(const float*)(wb + o2);
    float a3 = *(const float*)(wb + o3);
    float a4 = *(const float*)(wb + o4);
    float a5 = *(const float*)(wb + o5);
    float a6 = *(const float*)(wb + o6);
    float a7 = *(const float*)(wb + o7);
    return ((a0 + a1) + (a2 + a3)) + ((a4 + a5) + (a6 + a7));
}

// Tail gather: n in [1,8) real entries (uniform), rest literal 0.0f — same tree
// shape as gather8 with trailing zero pads => bit-identical contribution.
__device__ __forceinline__ float gatherN(const int* lst, int i, int n, const char* wb) {
    float a[8];
#pragma unroll
    for (int k = 0; k < 8; k++) {
        float v = 0.f;
        if (k < n) {
            int o = __builtin_amdgcn_readfirstlane(lst[i + k]);
            v = *(const float*)(wb + o);
        }
        a[k] = v;
    }
    return ((a[0] + a[1]) + (a[2] + a[3])) + ((a[4] + a[5]) + (a[6] + a[7]));
}

// ---------- K1: PosS2/PosS3 + zero-fills + per-image conv1 screen ----------
__global__ __launch_bounds__(256) void k_pre(const float* __restrict__ inp,
                                             const float* __restrict__ w1,
                                             const float* __restrict__ w2,
                                             const float* __restrict__ w3,
                                             float* __restrict__ PosS2, float* __restrict__ PosS3,
                                             unsigned char* __restrict__ ft1,
                                             unsigned char* __restrict__ nzc1,
                                             int* __restrict__ lcnt, int* __restrict__ list1) {
    int blk = blockIdx.x, tid = threadIdx.x;
    if (blk < 25) {
        int idx = blk * 256 + tid;
        if (idx < 6250) {
            int f = idx / 25, pos = idx - f * 25;
            float acc = 0.f;
#pragma unroll 30
            for (int c = 0; c < 90; c++) acc += w2[(size_t)(f * 90 + c) * 25 + pos];
            PosS2[pos * 256 + f] = acc;
        }
    } else if (blk < 45) {
        int idx = (blk - 25) * 256 + tid;
        if (idx < 5000) {
            int f = idx / 25, pos = idx - f * 25;
            float acc = 0.f;
#pragma unroll 50
            for (int c = 0; c < 250; c++) acc += w3[(size_t)(f * 250 + c) * 25 + pos];
            PosS3[pos * 200 + f] = acc;
        }
    } else if (blk < 678) {
        int i = (blk - 45) * 256 + tid;
        if (i < 162000) ((uint4*)ft1)[i] = uint4{0, 0, 0, 0};
    } else if (blk < 687) {
        // zero nzc1+nzc2+nzb1+nzb2+nzg2[0..3] (contiguous 34288 B = 2143 uint4)
        int i = (blk - 678) * 256 + tid;
        if (i < 2143) ((uint4*)nzc1)[i] = uint4{0, 0, 0, 0};
    } else {
        // per-image conv1 screen (32 blocks)
        int b = blk - 687;
        __shared__ unsigned char zl[36][36];
        __shared__ unsigned short rs[36][30];
        __shared__ float wm4[4];
        __shared__ float m1s;
        __shared__ int lc;
        for (int i = tid; i < 1296; i += 256) ((unsigned char*)zl)[i] = 0;
        if (tid == 0) lc = 0;
        __syncthreads();
#pragma unroll
        for (int k = 0; k < 4; k++) {
            int pix = tid + k * 256;
            int y = pix >> 5, x = pix & 31;
            const float* p = inp + (size_t)b * 276480 + y * 32 + x;   // t=0, c=0
            int z = 0;
#pragma unroll
            for (int c = 0; c < 18; c++) z += (p[(size_t)c * 1024] != 0.f);
            zl[y + 2][x + 2] = (unsigned char)z;
        }
        float m = 1e30f;
        const float4* w4 = (const float4*)w1;
        for (int i = tid; i < 19845; i += 256) {
            float4 v = w4[i];
            m = fminf(m, fminf(fminf(v.x, v.y), fminf(v.z, v.w)));
        }
        for (int o = 32; o > 0; o >>= 1) m = fminf(m, __shfl_down(m, o));
        if ((tid & 63) == 0) wm4[tid >> 6] = m;
        __syncthreads();
        if (tid == 0) m1s = fminf(fminf(wm4[0], wm4[1]), fminf(wm4[2], wm4[3]));
        __syncthreads();
        for (int i = tid; i < 1080; i += 256) {
            int y = i / 30, x = i - (i / 30) * 30;
            int s = 0;
#pragma unroll
            for (int d = 0; d < 7; d++) s += zl[y][x + d];
            rs[y][x] = (unsigned short)s;
        }
        __syncthreads();
        float m1 = m1s;
        for (int i = tid; i < 900; i += 256) {
            int oy = i / 30, ox = i - (i / 30) * 30;
            int s = 0;
#pragma unroll
            for (int d = 0; d < 7; d++) s += rs[oy + d][ox];
            if (!((float)s * m1 > 15.0f)) {
                int pos = atomicAdd(&lc, 1);
                list1[b * 900 + pos] = b * 900 + i;
            }
        }
        __syncthreads();
        if (tid == 0) lcnt[b] = lc;
    }
}

// ---------- K2: conv1 hard walks (512) + W2e/ft2-fill/nzc2/nzg2 (169) + W3s (16) + w2max (8) ----------
__global__ __launch_bounds__(256) void k_conv1(const float* __restrict__ inp,
                                               const float* __restrict__ w1,
                                               const float* __restrict__ w2,
                                               const float* __restrict__ PosS2,
                                               const float* __restrict__ PosS3,
                                               const int* __restrict__ lcnt,
                                               const int* __restrict__ list1,
                                               unsigned char* __restrict__ ft1,
                                               unsigned char* __restrict__ nzc1,
                                               unsigned char* __restrict__ nzb1,
                                               float* __restrict__ W2e,
                                               unsigned char* __restrict__ ft2,
                                               unsigned char* __restrict__ nzc2,
                                               int* __restrict__ nzg2,
                                               float* __restrict__ W3s) {
    __shared__ __align__(16) int slist[896];
    __shared__ int scnt;
    __shared__ int sbase[33];
    int blk = blockIdx.x, tid = threadIdx.x;
    if (blk < 512) {
        if (tid == 0) {
            int n = 0;
#pragma unroll
            for (int b = 0; b < NB; b++) { sbase[b] = n; n += lcnt[b]; }
            sbase[NB] = n;
        }
        __syncthreads();
        int n1 = sbase[NB];
        for (int it = blk; it < n1; it += 512) {
            __syncthreads();
            int sb = 0;
            while (sb < NB - 1 && it >= sbase[sb + 1]) sb++;
            int idx = list1[sb * 900 + (it - sbase[sb])];
            int b = idx / 900, p = idx - b * 900;
            int oy = p / 30, ox = p - oy * 30;
            unsigned char myft[4];
#pragma unroll
            for (int k = 0; k < 4; k++) {
                int j = tid + k * 256;
                unsigned char v = 255;
                if (j < 882) {
                    int dy = j / 126, rem = j - dy * 126;
                    int dx = rem / 18, c = rem - dx * 18;
                    int y = oy + dy - 2, x = ox + dx - 2;
                    v = 15;
                    if ((unsigned)y < 32u && (unsigned)x < 32u)
                        v = (inp[(size_t)b * 276480 + (size_t)c * 1024 + y * 32 + x] != 0.f) ? 0 : 200;
                }
                myft[k] = v;
            }
            int f = tid < 90 ? tid : 89;
            const char* wb = (const char*)(w1 + (size_t)f * 882);   // [f][c][ky][kx]
            float acc = 0.f; int ftv = 15;
            for (int s = 0; s < 15; s++) {
                if (s == 1) {
#pragma unroll
                    for (int k = 0; k < 4; k++) {
                        if (myft[k] == 200) {
                            int j = tid + k * 256;
                            int dy = j / 126, rem = j - dy * 126;
                            int dx = rem / 18, c = rem - dx * 18;
                            int y = oy + dy - 2, x = ox + dx - 2;
                            const float* q = inp + (size_t)b * 276480 + (size_t)c * 1024 + y * 32 + x;
                            int cf = 0;
#pragma unroll
                            for (int t = 1; t < NT; t++) cf += (q[(size_t)t * 18432] != 0.f);
                            myft[k] = (unsigned char)(15 - cf);
                        }
                    }
                }
                if (tid == 0) scnt = 0;
                __syncthreads();
#pragma unroll
                for (int k = 0; k < 4; k++) {
                    if ((int)myft[k] == s) {
                        int j = tid + k * 256;
                        int dy = j / 126, rem = j - dy * 126;
                        int dx = rem / 18, c = rem - dx * 18;
                        int pp = atomicAdd(&scnt, 1);
                        slist[pp] = (c * 49 + dy * 7 + dx) * 4;     // byte offset in w1[f]
                    }
                }
                __syncthreads();
                int c0 = scnt;
                int full = c0 & ~7;
                for (int i = 0; i < full; i += 8) acc += gather8(slist, i, wb);
                int nt = c0 - full;
                if (nt) acc += gatherN(slist, full, nt, wb);
                if (ftv == 15 && acc > 15.0f) ftv = s;
                if (__syncthreads_and(ftv != 15)) break;
            }
            if (tid < 90) {
                ft1[(size_t)idx * 90 + tid] = (unsigned char)ftv;
                if (ftv != 0) { nzc1[idx] = 1; nzb1[b] = 1; }
            }
            __syncthreads();
        }
    } else if (blk < 681) {
        // per-p: W2e (same pos-ascending order) + ft2 fill + nzc2 init + nzg2
        int p = blk - 512;
        int oy = p / 13, ox = p - oy * 13;
        int f = tid < 250 ? tid : 249;
        float W = 0.f;
#pragma unroll
        for (int pos = 0; pos < 25; pos++) {
            int r = pos / 5, x = pos - r * 5;
            int gy = oy + r, gx = ox + x;
            if (!(gy == 0 || gy == 16 || gx == 0 || gx == 16)) W += PosS2[pos * 256 + f];
        }
        if (tid < 250) W2e[p * 256 + tid] = W;
        unsigned char v = (W > 10.0f) ? 0 : 15;
        if (tid < 250)
            for (int b = 0; b < NB; b++) ft2[(size_t)(b * 169 + p) * 250 + tid] = v;
        int nz = (tid < 250 && W <= 10.0f) ? 1 : 0;
        int any = __syncthreads_or(nz);
        if (tid < NB) nzc2[tid * 169 + p] = (unsigned char)any;
        if (tid == 0 && any) nzg2[0] = 1;
    } else if (blk < 697) {
        // per-px: W3s (same (r,x)-ascending order)
        int px = blk - 681;
        int f = tid < 200 ? tid : 199;
        int oy = px >> 2, ox = px & 3;
        int r0 = max(0, 2 - oy), r1 = min(4, 5 - oy);
        int x0 = max(0, 2 - ox), x1 = min(4, 5 - ox);
        float s = 0.f;
        for (int r = r0; r <= r1; r++)
            for (int x = x0; x <= x1; x++) s += PosS3[(r * 5 + x) * 200 + f];
        if (tid < 200) W3s[px * 200 + tid] = s;
    } else {
        // w2 global max (8 blocks) -> nzg2[1] via int atomicMax (w2 > 0)
        __shared__ float wmx[4];
        float m = -1e30f;
        const float4* w4 = (const float4*)w2;
        for (int i = (blk - 697) * 256 + tid; i < 140625; i += 2048) {
            float4 v = w4[i];
            m = fmaxf(m, fmaxf(fmaxf(v.x, v.y), fmaxf(v.z, v.w)));
        }
        for (int o = 32; o > 0; o >>= 1) m = fmaxf(m, __shfl_down(m, o));
        if ((tid & 63) == 0) wmx[tid >> 6] = m;
        __syncthreads();
        if (tid == 0) {
            float mm = fmaxf(fmaxf(wmx[0], wmx[1]), fmaxf(wmx[2], wmx[3]));
            atomicMax(nzg2 + 1, __float_as_int(mm));
        }
    }
}

// ---------- K3: conv2 screen + two-tier skip + rare walks + out pot fill ----------
__global__ __launch_bounds__(256) void k_conv2(const unsigned char* __restrict__ ft1,
                                               const unsigned char* __restrict__ nzc1,
                                               const unsigned char* __restrict__ nzb1,
                                               const float* __restrict__ w2,
                                               const float* __restrict__ W2e,
                                               const float* __restrict__ W3s,
                                               const int* __restrict__ m2,
                                               unsigned char* __restrict__ ft2,
                                               unsigned char* __restrict__ nzc2,
                                               unsigned char* __restrict__ nzb2,
                                               float* __restrict__ out) {
    constexpr int PADCAP = 2250 + 15 * 8;
    __shared__ __align__(16) int perm[PADCAP];
    __shared__ int start[16], cur[16], rcnt[15];
    __shared__ int cntCs, anynz, dcnt;
    int blk = blockIdx.x, tid = threadIdx.x;
    if (blk >= 5408) {
        int i = (blk - 5408) * 256 + tid;          // < 384000 exactly (1500 blocks)
        int g = i * 4;
        int px0 = g & 15;
        int f = (g >> 4) % 200;
        float4 v;
        v.x = W3s[(px0 + 0) * 200 + f];
        v.y = W3s[(px0 + 1) * 200 + f];
        v.z = W3s[(px0 + 2) * 200 + f];
        v.w = W3s[(px0 + 3) * 200 + f];
        *(float4*)(out + 32 + (size_t)g) = v;
        return;
    }
    int idx = blk;
    int b = idx / 169, p = idx - b * 169;
    if (nzb1[b] == 0) return;
    int oy = p / 13, ox = p - oy * 13;
    int gy0 = max(1, oy), gy1 = min(15, oy + 4);
    int gx0 = max(1, ox), gx1 = min(15, ox + 4);
    int y0 = 2 * (gy0 - 1), y1 = 2 * (gy1 - 1) + 1;
    int x0 = 2 * (gx0 - 1), x1 = 2 * (gx1 - 1) + 1;
    int Wd = x1 - x0 + 1, cells = (y1 - y0 + 1) * Wd;
    const unsigned char* nb = nzc1 + b * 900;
    if (tid == 0) dcnt = 0;
    int v = 0;
    if (tid < cells) { int yy = y0 + tid / Wd, xx = x0 + tid % Wd; v = nb[yy * 30 + xx]; }
    int dirty = __syncthreads_or(v);
    if (!dirty) return;
    // TIER-1 SKIP (before any pooling load): nnz <= 90 * (#dirty pooled cells).
    int PW = gx1 - gx0 + 1, pcells = (gy1 - gy0 + 1) * PW;
    if (tid < pcells) {
        int gy = gy0 + tid / PW, gx = gx0 + tid % PW;
        const unsigned char* q = nb + (2 * (gy - 1)) * 30 + 2 * (gx - 1);
        int d = q[0] | q[1] | q[30] | q[31];
        if (d) atomicAdd(&dcnt, 1);
    }
    __syncthreads();
    int f = tid < 250 ? tid : 249;
    float W = W2e[p * 256 + f];
    float m2f = __int_as_float(m2[1]);
    int skip1 = __syncthreads_and(W - m2f * (float)(90 * dcnt) > 10.0f);
    if (skip1) return;   // prefill (ft2=0, nzc2=0) provably equals the walk output
    // pooling + exact nnz
    const unsigned char* fb = ft1 + (size_t)b * 81000;
    if (tid == 0) { cntCs = 0; anynz = 0; }
    if (tid < 16) cur[tid] = 0;
    unsigned char myft[9];
    int nc = 0;
#pragma unroll
    for (int k = 0; k < 9; k++) {
        int j = tid + k * 256;
        myft[k] = 0;
        if (j < 2250) {
            int r = j / 450, rem = j - r * 450;
            int x = rem / 90, c = rem - x * 90;
            int gy = oy + r, gx = ox + x;
            if (gy >= 1 && gy <= 15 && gx >= 1 && gx <= 15) {
                const unsigned char* q = fb + ((size_t)((gy - 1) * 2) * 30 + (gx - 1) * 2) * 90 + c;
                int m = q[0];
                m = min(m, (int)q[90]);
                m = min(m, (int)q[2700]);
                m = min(m, (int)q[2790]);
                myft[k] = (unsigned char)m;
            }
        }
        nc += (myft[k] >= 1);
    }
    for (int o = 32; o > 0; o >>= 1) nc += __shfl_down(nc, o);
    __syncthreads();
    if ((tid & 63) == 0) atomicAdd(&cntCs, nc);
    __syncthreads();
    int ftv;
    if (cntCs == 0) {
        ftv = (W > 10.0f) ? 0 : 15;
    } else {
        // TIER-2 SKIP (exact nnz): write-free, same proof.
        int skip2 = __syncthreads_and(W - m2f * (float)cntCs > 10.0f);
        if (skip2) return;
#pragma unroll
        for (int k = 0; k < 9; k++) { int vv = myft[k]; if (vv >= 1) atomicAdd(&cur[vv - 1], 1); }
        __syncthreads();
        if (tid < 15) rcnt[tid] = cur[tid];
        if (tid == 0) {
            int s = 0;
#pragma unroll
            for (int j = 0; j < 15; j++) { int c = cur[j]; start[j] = s; s += (c + 7) & ~7; }
            start[15] = s;
        }
        __syncthreads();
        if (tid < 15) cur[tid] = start[tid];
        __syncthreads();
#pragma unroll
        for (int k = 0; k < 9; k++) {
            int vv = myft[k];
            if (vv >= 1) {
                int j = tid + k * 256;
                int r = j / 450, rem = j - r * 450;
                int x = rem / 90, c = rem - x * 90;
                int pp = atomicAdd(&cur[vv - 1], 1);
                perm[pp] = (c * 25 + (r * 5 + x)) * 4;   // byte offset in w2[f]
            }
        }
        __syncthreads();
        const char* wb = (const char*)(w2 + (size_t)f * 2250);   // [f][c][pos]
        float R = 0.f; int ft = 15;
        for (int j = 14; j >= 0; j--) {
            int sjb = start[j];
            int rc = rcnt[j];
            int rend = sjb + rc;
            int i = sjb;
            for (; i + 8 <= rend; i += 8) R += gather8(perm, i, wb);
            int nt = rend - i;
            if (nt > 0) R += gatherN(perm, i, nt, wb);
            float pot = W - R;
            if (pot > 10.0f) ft = j;
            if (sjb == 0) { if (pot > 10.0f) ft = 0; break; }
            if (__all(pot <= 10.0f)) break;
        }
        ftv = ft;
    }
    if (tid < 250) {
        ft2[(size_t)idx * 250 + tid] = (unsigned char)ftv;
        if (ftv != 0) anynz = 1;
    }
    __syncthreads();
    if (tid == 0) {
        nzc2[idx] = (unsigned char)(anynz ? 1 : 0);
        if (anynz) nzb2[b] = 1;
    }
}

// ---------- K4: per-image conv3 (prefiltered screens + rare walks, direct-w3) + winner ----------
__global__ __launch_bounds__(256) void k_conv3w(const unsigned char* __restrict__ ft2,
                                                const unsigned char* __restrict__ nzc2,
                                                const unsigned char* __restrict__ nzb2,
                                                const int* __restrict__ nzg2,
                                                const float* __restrict__ w3,
                                                const float* __restrict__ W3s,
                                                float* __restrict__ out) {
    constexpr int PADCAP = 4000 + 15 * 8;
    __shared__ __align__(16) int perm[PADCAP];
    __shared__ int start[16], cur[16], rcnt[15];
    __shared__ int fbs[16], rowb[16];
    __shared__ float sv[256];
    __shared__ int   si[256];
    int b = blockIdx.x, tid = threadIdx.x;
    int maybe = nzg2[0] | (int)nzb2[b];
    if (maybe) {
        for (int p = 0; p < 16; p++) {
            int oy = p >> 2, ox = p & 3;
            int r0 = max(0, 2 - oy), r1 = min(4, 5 - oy);
            int x0 = max(0, 2 - ox), x1 = min(4, 5 - ox);
            int py0 = oy + r0 - 2, py1 = oy + r1 - 2;
            int qx0 = ox + x0 - 2, qx1 = ox + x1 - 2;
            int sy0 = 3 * py0, sy1 = 3 * py1 + 2;
            int sx0 = 3 * qx0, sx1 = 3 * qx1 + 2;
            int Wd = sx1 - sx0 + 1, cells = (sy1 - sy0 + 1) * Wd;
            const unsigned char* nb2 = nzc2 + b * 169;
            int v = 0;
            if (tid < cells) { int yy = sy0 + tid / Wd, xx = sx0 + tid % Wd; v = nb2[yy * 13 + xx]; }
            int dirty = __syncthreads_or(v);
            if (!dirty) continue;
            int VR = r1 - r0 + 1, VC = x1 - x0 + 1;
            int NP = VR * VC, NV = NP * 250;
            const unsigned char* fb = ft2 + (size_t)b * 42250;
            if (tid < NP) {
                int rv = tid / VC, xv = tid - rv * VC;
                int py = oy + r0 + rv - 2, pxx = ox + x0 + xv - 2;
                fbs[tid]  = (py * 3 * 13 + pxx * 3) * 250;
                rowb[tid] = (r0 + rv) * 5 + (x0 + xv);          // position index 0..24
            }
            if (tid < 16) cur[tid] = 0;
            __syncthreads();
            unsigned char myft[16];
#pragma unroll
            for (int k = 0; k < 16; k++) {
                int i = tid + k * 256;
                myft[k] = 0;
                if (i < NV) {
                    int posv = i / 250, c = i - posv * 250;
                    const unsigned char* q = fb + fbs[posv] + c;
                    int m = q[0];
#pragma unroll
                    for (int dy = 0; dy < 3; dy++)
#pragma unroll
                        for (int dx = 0; dx < 3; dx++)
                            if (dy | dx) m = min(m, (int)q[(dy * 13 + dx) * 250]);
                    myft[k] = (unsigned char)m;
                }
            }
#pragma unroll
            for (int k = 0; k < 16; k++) { int vv = myft[k]; if (vv >= 1) atomicAdd(&cur[vv - 1], 1); }
            __syncthreads();
            if (tid < 15) rcnt[tid] = cur[tid];
            if (tid == 0) {
                int s = 0;
#pragma unroll
                for (int j = 0; j < 15; j++) { int c = cur[j]; start[j] = s; s += (c + 7) & ~7; }
                start[15] = s;
            }
            __syncthreads();
            if (tid < 15) cur[tid] = start[tid];
            __syncthreads();
#pragma unroll
            for (int k = 0; k < 16; k++) {
                int vv = myft[k];
                if (vv >= 1) {
                    int i = tid + k * 256;
                    int posv = i / 250, c = i - posv * 250;
                    int pp = atomicAdd(&cur[vv - 1], 1);
                    perm[pp] = (c * 25 + rowb[posv]) * 4;       // byte offset in w3[f]
                }
            }
            __syncthreads();

            int f = tid < 200 ? tid : 199;
            const char* wb = (const char*)(w3 + (size_t)f * 6250);   // [f][c][pos]
            float W = W3s[p * 200 + f];
            float* o = out + 32 + ((size_t)b * NT) * 3200 + f * 16 + p;
            float R = 0.f;
            for (int j = 14; j >= 0; j--) {
                int sjb = start[j];
                int rc = rcnt[j];
                int rend = sjb + rc;
                int i = sjb;
                for (; i + 8 <= rend; i += 8) R += gather8(perm, i, wb);
                int nt = rend - i;
                if (nt > 0) R += gatherN(perm, i, nt, wb);
                float pot = W - R;
                if (tid < 200) o[(size_t)j * 3200] = pot;
                if (sjb == 0) {
                    for (int jj = j - 1; jj >= 0; jj--)
                        if (tid < 200) o[(size_t)jj * 3200] = pot;
                    break;
                }
            }
            __syncthreads();
        }
    }
    __syncthreads();
    // winner (verified body)
    const float* p14 = out + 32 + ((size_t)b * NT + 14) * 3200;
    float m = 0.f;
    for (int j = tid; j < 3200; j += 256) {
        float v = p14[j];
        if (v > 0.f && v > m) m = v;
    }
    sv[tid] = m;
    __syncthreads();
    for (int s = 128; s > 0; s >>= 1) {
        if (tid < s) sv[tid] = fmaxf(sv[tid], sv[tid + s]);
        __syncthreads();
    }
    float vofs = 15.f * sv[0];
    __syncthreads();
    float bestv = 0.f; int besti = 0x3fffffff;
    for (int j = tid; j < 3200; j += 256) {
        float v = p14[j];
        float tot = (v > 0.f) ? v + vofs : 0.f;
        if (tot > bestv) { bestv = tot; besti = j; }
    }
    sv[tid] = bestv; si[tid] = besti;
    __syncthreads();
    for (int s = 128; s > 0; s >>= 1) {
        if (tid < s) {
            if (sv[tid + s] > sv[tid] || (sv[tid + s] == sv[tid] && si[tid + s] < si[tid])) {
                sv[tid] = sv[tid + s]; si[tid] = si[tid + s];
            }
        }
        __syncthreads();
    }
    if (tid == 0) {
        float mx = sv[0];
        int cls = (mx != 0.f) ? ((si[0] / 16) / 20) : -1;
        out[b] = (float)cls;
    }
}

extern "C" void kernel_launch(void* const* d_in, const int* in_sizes, int n_in,
                              void* d_out, int out_size, void* d_ws, size_t ws_size,
                              hipStream_t stream) {
    const float* inp = (const float*)d_in[0];
    const float* w1  = (const float*)d_in[1];
    const float* w2  = (const float*)d_in[2];
    const float* w3  = (const float*)d_in[3];
    float* out = (float*)d_out;

    unsigned char* ws   = (unsigned char*)d_ws;
    unsigned char* ft1  = ws + 0;
    unsigned char* ft2  = ws + 2592000;
    float* PosS2 = (float*)(ws + 11513728);
    float* PosS3 = (float*)(ws + 11539328);
    float* W2e   = (float*)(ws + 11559328);
    float* W3s   = (float*)(ws + 11732384);
    unsigned char* nzc1 = ws + 11786912;
    unsigned char* nzc2 = ws + 11815712;
    unsigned char* nzb1 = ws + 11821120;
    unsigned char* nzb2 = ws + 11821152;
    int* nzg2  = (int*)(ws + 11821184);
    int* lcnt  = (int*)(ws + 11821200);
    int* list1 = (int*)(ws + 11821440);

    hipLaunchKernelGGL(k_pre, dim3(719), dim3(256), 0, stream,
                       inp, w1, w2, w3, PosS2, PosS3, ft1, nzc1, lcnt, list1);
    hipLaunchKernelGGL(k_conv1, dim3(705), dim3(256), 0, stream,
                       inp, w1, w2, PosS2, PosS3, lcnt, list1, ft1, nzc1, nzb1, W2e, ft2, nzc2, nzg2, W3s);
    hipLaunchKernelGGL(k_conv2, dim3(6908), dim3(256), 0, stream,
                       ft1, nzc1, nzb1, w2, W2e, W3s, nzg2, ft2, nzc2, nzb2, out);
    hipLaunchKernelGGL(k_conv3w, dim3(NB), dim3(256), 0, stream,
                       ft2, nzc2, nzb2, nzg2, w3, W3s, out);
}